// Round 7
// baseline (401.989 us; speedup 1.0000x reference)
//
#include <hip/hip_runtime.h>

// ---------------------------------------------------------------------------
// AttentionPooling: out[b,o] = sum_p softmax_over_o(qk^T)[o,p] * vbar[b,p]
//   q = wq x + bq, k = wk x + bk  (1x1 conv == GEMM, M=64 K=512 N=4096/batch)
//   vbar[b,p] = wv . mean_n x[b,:,n] + bv   (v never materialized)
// Precision: fp32 emulated via bf16 hi/lo split, 3 MFMA passes (wh*xh + wl*xh
// + wh*xl) accumulating fp32 -> ~2^-16 relative.
//
// R7 vs R6 (398.5us):
//  - KC 32 -> 64: 8 chunks instead of 16, halving barrier-drain events
//    (32 -> 16). Same 2-barrier body, 2 MFMA k-steps per chunk.
//  - row stride 72 ushorts (144B = stride of 1 bank-group per row): x writes,
//    x reads, weight reads/writes all minimum-aliasing -- swizzle dropped.
//  - LDS 72KiB/block, still 2 blocks/CU at (256,2). VGPR peak ~190 < 256 cap.
// ---------------------------------------------------------------------------

typedef __attribute__((ext_vector_type(8))) short short8;          // 8 bf16
typedef __attribute__((ext_vector_type(4))) float floatx4;
typedef __attribute__((ext_vector_type(4))) unsigned short ushort4v;
typedef __attribute__((ext_vector_type(8))) unsigned short ushort8v;

#define MFMA16(a, b, c) __builtin_amdgcn_mfma_f32_16x16x32_bf16((a), (b), (c), 0, 0, 0)

__device__ __forceinline__ unsigned short f2bf(float f) {
  unsigned int u = __float_as_uint(f);
  u = u + 0x7fffu + ((u >> 16) & 1u);   // RNE
  return (unsigned short)(u >> 16);
}
__device__ __forceinline__ float bf2f(unsigned short h) {
  return __uint_as_float(((unsigned int)h) << 16);
}

constexpr int CB = 32;        // batch
constexpr int CC = 512;       // channels
constexpr int CO = 64;        // C/8
constexpr int NN = 4096;      // H*W
constexpr int NT = 128;       // n-tile per workgroup
constexpr int KC = 64;        // c-chunk staged per iteration
constexpr int NCH = CC / KC;  // 8 chunks

// Row stride 72 ushorts (144B): 16B-aligned rows, and 144B = 36 dwords ==
// 4 bank-groups, so consecutive rows start one 16B bank-group over ->
// minimum aliasing for all b128 access patterns here (verified by hand).
constexpr int XROW = 72;      // x rows: KC(64) + 8 pad
constexpr int QROW = 72;      // q/k tile rows: 64 + 8 pad

// LDS offsets (ushort units), projection phase:
constexpr int WQH = 0;        // wq hi  [64][72]
constexpr int WQL = 4608;     // wq lo
constexpr int WKH = 9216;     // wk hi
constexpr int WKL = 13824;    // wk lo
constexpr int XHI = 18432;    // x^T hi [128][72]
constexpr int XLO = 27648;    // x^T lo
constexpr int SMEM_U = 36864; // 72 KiB total
// logits phase overlays the weight arrays (dead after the K-loop):
constexpr int QHI = 0, QLO = 4608, KHI = 9216, KLO = 13824;  // [64][72] each

constexpr int WB_ELEMS = CO * CC;  // 32768 ushorts per array (qh, ql, kh, kl)
constexpr int ZERO_N = CB * CO * CO + CB * CC;  // 147456 floats to zero

// ---- fused: zero logits/xsum + one-time weight split to bf16 hi/lo --------
__global__ __launch_bounds__(256) void init_kernel(
    const float* __restrict__ wq, const float* __restrict__ wk,
    unsigned short* __restrict__ wbuf, float* __restrict__ zp)
{
  const int i = blockIdx.x * 256 + threadIdx.x;
  if (i < ZERO_N) zp[i] = 0.0f;
  if (i < WB_ELEMS) {
    const float q = wq[i], k = wk[i];
    const unsigned short qh = f2bf(q), kh = f2bf(k);
    wbuf[i]                 = qh;
    wbuf[WB_ELEMS + i]      = f2bf(q - bf2f(qh));
    wbuf[2 * WB_ELEMS + i]  = kh;
    wbuf[3 * WB_ELEMS + i]  = f2bf(k - bf2f(kh));
  }
}

__global__ __launch_bounds__(256, 2) void proj_kernel(
    const float* __restrict__ x, const unsigned short* __restrict__ wbuf,
    const float* __restrict__ bq, const float* __restrict__ bk,
    float* __restrict__ logits, float* __restrict__ xsum)
{
  __shared__ __align__(16) unsigned short smem[SMEM_U];

  const int t    = threadIdx.x;
  const int lane = t & 63;
  const int wave = t >> 6;
  const int quad = lane >> 4;
  const int l15  = lane & 15;
  const int b    = blockIdx.x >> 5;   // /32 tiles
  const int tile = blockIdx.x & 31;
  const int n0   = tile * NT;
  const int nlow = t & 31;            // n sub-index for staging
  const int chi  = t >> 5;            // c slot 0..7 (8 c's each) for staging
  // weight staging: two flat ids per thread, row = flat>>3, slot cf = flat&7
  const int wrow0 = t >> 3;           // rows 0..31   (u=0)
  const int wrow1 = (t + 256) >> 3;   // rows 32..63  (u=1)
  const int wcf   = (t & 7) * 8;      // slot col (ushorts)

  floatx4 accq[4][2], acck[4][2];     // q,k tiles: 4 m-frags x 2 n-frags/wave
#pragma unroll
  for (int mf = 0; mf < 4; ++mf)
#pragma unroll
    for (int nf = 0; nf < 2; ++nf) {
      accq[mf][nf] = (floatx4)0.0f;
      acck[mf][nf] = (floatx4)0.0f;
    }

  const float* xb = x + (size_t)b * CC * NN + n0;

  // ---- prefetch chunk 0 into registers: 4 n's x 8 c's per thread ----
  float xr[32];
#pragma unroll
  for (int i = 0; i < 4; ++i)
#pragma unroll
    for (int j = 0; j < 8; ++j)
      xr[i * 8 + j] = xb[(size_t)(chi * 8 + j) * NN + i * 32 + nlow];

  for (int ch = 0; ch < NCH; ++ch) {
    const int c0 = ch * KC;
    __syncthreads();  // previous chunk's LDS reads done before overwrite

    // ---- issue weight loads early (L2-resident after first WGs) ----
    const unsigned short* ws0 = wbuf + (size_t)wrow0 * CC + c0 + wcf;
    const unsigned short* ws1 = wbuf + (size_t)wrow1 * CC + c0 + wcf;
    const ushort8v a0 = *reinterpret_cast<const ushort8v*>(ws0);
    const ushort8v a1 = *reinterpret_cast<const ushort8v*>(ws0 + WB_ELEMS);
    const ushort8v a2 = *reinterpret_cast<const ushort8v*>(ws0 + 2 * WB_ELEMS);
    const ushort8v a3 = *reinterpret_cast<const ushort8v*>(ws0 + 3 * WB_ELEMS);
    const ushort8v c0v = *reinterpret_cast<const ushort8v*>(ws1);
    const ushort8v c1v = *reinterpret_cast<const ushort8v*>(ws1 + WB_ELEMS);
    const ushort8v c2v = *reinterpret_cast<const ushort8v*>(ws1 + 2 * WB_ELEMS);
    const ushort8v c3v = *reinterpret_cast<const ushort8v*>(ws1 + 3 * WB_ELEMS);

    // ---- convert prefetched x chunk -> LDS transposed [n][c] hi/lo ----
    float xs_part[8];
#pragma unroll
    for (int j = 0; j < 8; ++j) xs_part[j] = 0.f;
#pragma unroll
    for (int i = 0; i < 4; ++i) {
      const int n = i * 32 + nlow;
      ushort8v h, l;
#pragma unroll
      for (int j = 0; j < 8; ++j) {
        const float v = xr[i * 8 + j];
        xs_part[j] += v;
        h[j] = f2bf(v);
        l[j] = f2bf(v - bf2f(h[j]));
      }
      *reinterpret_cast<ushort8v*>(&smem[XHI + n * XROW + chi * 8]) = h;
      *reinterpret_cast<ushort8v*>(&smem[XLO + n * XROW + chi * 8]) = l;
    }
#pragma unroll
    for (int j = 0; j < 8; ++j) {   // reduce 32 lanes (same c) -> 1 atomic
      float v = xs_part[j];
      v += __shfl_xor(v, 16); v += __shfl_xor(v, 8);
      v += __shfl_xor(v, 4);  v += __shfl_xor(v, 2); v += __shfl_xor(v, 1);
      if ((lane & 31) == 0) atomicAdd(&xsum[b * CC + c0 + chi * 8 + j], v);
    }

    // ---- weight copies into LDS rows ----
    *reinterpret_cast<ushort8v*>(&smem[WQH + wrow0 * XROW + wcf]) = a0;
    *reinterpret_cast<ushort8v*>(&smem[WQL + wrow0 * XROW + wcf]) = a1;
    *reinterpret_cast<ushort8v*>(&smem[WKH + wrow0 * XROW + wcf]) = a2;
    *reinterpret_cast<ushort8v*>(&smem[WKL + wrow0 * XROW + wcf]) = a3;
    *reinterpret_cast<ushort8v*>(&smem[WQH + wrow1 * XROW + wcf]) = c0v;
    *reinterpret_cast<ushort8v*>(&smem[WQL + wrow1 * XROW + wcf]) = c1v;
    *reinterpret_cast<ushort8v*>(&smem[WKH + wrow1 * XROW + wcf]) = c2v;
    *reinterpret_cast<ushort8v*>(&smem[WKL + wrow1 * XROW + wcf]) = c3v;

    // ---- prefetch next x chunk; latency hides under MFMA phase ----
    if (ch + 1 < NCH) {
      const int c0n = c0 + KC;
#pragma unroll
      for (int i = 0; i < 4; ++i)
#pragma unroll
        for (int j = 0; j < 8; ++j)
          xr[i * 8 + j] = xb[(size_t)(c0n + chi * 8 + j) * NN + i * 32 + nlow];
    }
    __syncthreads();

    // ---- MFMA: wave w covers n-local [w*32, w*32+32); 2 k-steps/chunk ----
#pragma unroll
    for (int ks = 0; ks < 2; ++ks) {
      const int co = ks * 32 + quad * 8;   // c offset within row
      short8 xh[2], xl[2];
#pragma unroll
      for (int nf = 0; nf < 2; ++nf) {
        const int nr = wave * 32 + nf * 16 + l15;
        xh[nf] = *reinterpret_cast<const short8*>(&smem[XHI + nr * XROW + co]);
        xl[nf] = *reinterpret_cast<const short8*>(&smem[XLO + nr * XROW + co]);
      }
#pragma unroll
      for (int mf = 0; mf < 4; ++mf) {
        const int orow = mf * 16 + l15;
        const short8 aqh = *reinterpret_cast<const short8*>(&smem[WQH + orow * XROW + co]);
        const short8 aql = *reinterpret_cast<const short8*>(&smem[WQL + orow * XROW + co]);
        const short8 akh = *reinterpret_cast<const short8*>(&smem[WKH + orow * XROW + co]);
        const short8 akl = *reinterpret_cast<const short8*>(&smem[WKL + orow * XROW + co]);
#pragma unroll
        for (int nf = 0; nf < 2; ++nf) {
          accq[mf][nf] = MFMA16(aqh, xh[nf], accq[mf][nf]);
          accq[mf][nf] = MFMA16(aql, xh[nf], accq[mf][nf]);
          accq[mf][nf] = MFMA16(aqh, xl[nf], accq[mf][nf]);
          acck[mf][nf] = MFMA16(akh, xh[nf], acck[mf][nf]);
          acck[mf][nf] = MFMA16(akl, xh[nf], acck[mf][nf]);
          acck[mf][nf] = MFMA16(akh, xl[nf], acck[mf][nf]);
        }
      }
    }
  }

  // ---- add biases (C/D layout: row o = mf*16 + quad*4 + reg, col = n) ----
#pragma unroll
  for (int mf = 0; mf < 4; ++mf)
#pragma unroll
    for (int r = 0; r < 4; ++r) {
      const int o = mf * 16 + quad * 4 + r;
      const float bqv = bq[o], bkv = bk[o];
#pragma unroll
      for (int nf = 0; nf < 2; ++nf) {
        accq[mf][nf][r] += bqv;
        acck[mf][nf][r] += bkv;
      }
    }

  // ---- logits partial: S = q k^T over this n-tile, K split in two halves ----
  floatx4 accS[4];
#pragma unroll
  for (int mf = 0; mf < 4; ++mf) accS[mf] = (floatx4)0.0f;

  for (int hh = 0; hh < 2; ++hh) {
    __syncthreads();
    if ((wave >> 1) == hh) {   // waves owning n-local [hh*64, hh*64+64) write
      const int nbase = (wave & 1) * 32;
#pragma unroll
      for (int mf = 0; mf < 4; ++mf)
#pragma unroll
        for (int nf = 0; nf < 2; ++nf)
#pragma unroll
          for (int r = 0; r < 4; ++r) {
            const int o  = mf * 16 + quad * 4 + r;
            const int nc = nbase + nf * 16 + l15;
            const float qv = accq[mf][nf][r];
            const float kv = acck[mf][nf][r];
            const unsigned short qh = f2bf(qv);
            const unsigned short kh = f2bf(kv);
            smem[QHI + o * QROW + nc] = qh;
            smem[QLO + o * QROW + nc] = f2bf(qv - bf2f(qh));
            smem[KHI + o * QROW + nc] = kh;
            smem[KLO + o * QROW + nc] = f2bf(kv - bf2f(kh));
          }
    }
    __syncthreads();
#pragma unroll
    for (int ks = 0; ks < 2; ++ks) {
      const short8 bh = *reinterpret_cast<const short8*>(
          &smem[KHI + (wave * 16 + l15) * QROW + ks * 32 + quad * 8]);
      const short8 bl = *reinterpret_cast<const short8*>(
          &smem[KLO + (wave * 16 + l15) * QROW + ks * 32 + quad * 8]);
#pragma unroll
      for (int mf = 0; mf < 4; ++mf) {
        const short8 ah = *reinterpret_cast<const short8*>(
            &smem[QHI + (mf * 16 + l15) * QROW + ks * 32 + quad * 8]);
        const short8 al = *reinterpret_cast<const short8*>(
            &smem[QLO + (mf * 16 + l15) * QROW + ks * 32 + quad * 8]);
        accS[mf] = MFMA16(ah, bh, accS[mf]);
        accS[mf] = MFMA16(al, bh, accS[mf]);
        accS[mf] = MFMA16(ah, bl, accS[mf]);
      }
    }
  }

  // accumulate into global logits[b][o][p]
#pragma unroll
  for (int mf = 0; mf < 4; ++mf)
#pragma unroll
    for (int r = 0; r < 4; ++r) {
      const int o = mf * 16 + quad * 4 + r;
      const int p = wave * 16 + l15;
      atomicAdd(&logits[((size_t)b * CO + o) * CO + p], accS[mf][r]);
    }
}

__global__ __launch_bounds__(256) void finalize_kernel(
    const float* __restrict__ wv, const float* __restrict__ bv,
    const float* __restrict__ logits, const float* __restrict__ xsum,
    float* __restrict__ out)
{
  __shared__ float ls[CO * 65];
  __shared__ float xs_s[CC];
  __shared__ float vbar_s[CO], w2_s[CO], cmax_s[CO];
  const int t = threadIdx.x;
  const int b = blockIdx.x;

  for (int i = t; i < CC; i += 256) xs_s[i] = xsum[b * CC + i];
#pragma unroll
  for (int i = 0; i < 16; ++i) {
    const int idx = t + i * 256;          // 0..4095
    ls[(idx >> 6) * 65 + (idx & 63)] = logits[(size_t)b * CO * CO + idx];
  }
  __syncthreads();

  // vbar[p] = (wv[p,:] . xsum[b,:]) / N + bv[p]; 4 threads per p
  {
    const int p = t >> 2, part = t & 3;
    float s = 0.f;
    const float* wr = wv + (size_t)p * CC + part * 128;
    const float* xr = xs_s + part * 128;
#pragma unroll 4
    for (int c = 0; c < 128; ++c) s += wr[c] * xr[c];
    s += __shfl_xor(s, 1); s += __shfl_xor(s, 2);
    if (part == 0) vbar_s[p] = s * (1.0f / 4096.0f) + bv[p];
  }
  __syncthreads();

  if (t < CO) {  // column stats: softmax over rows o for column p=t
    float m = -1e30f;
    for (int o = 0; o < CO; ++o) m = fmaxf(m, ls[o * 65 + t]);
    float sum = 0.f;
    for (int o = 0; o < CO; ++o) sum += __expf(ls[o * 65 + t] - m);
    cmax_s[t] = m;
    w2_s[t]   = vbar_s[t] / sum;
  }
  __syncthreads();

  if (t < CO) {  // out[b,o] = sum_p exp(l[o,p]-cmax[p]) * vbar[p]/colsum[p]
    float acc = 0.f;
    for (int p = 0; p < CO; ++p)
      acc += __expf(ls[t * 65 + p] - cmax_s[p]) * w2_s[p];
    out[b * CO + t] = acc;
  }
}

extern "C" void kernel_launch(void* const* d_in, const int* in_sizes, int n_in,
                              void* d_out, int out_size, void* d_ws, size_t ws_size,
                              hipStream_t stream) {
  const float* x  = (const float*)d_in[0];
  const float* wq = (const float*)d_in[1];
  const float* bq = (const float*)d_in[2];
  const float* wk = (const float*)d_in[3];
  const float* bk = (const float*)d_in[4];
  const float* wv = (const float*)d_in[5];
  const float* bv = (const float*)d_in[6];
  float* out = (float*)d_out;

  // workspace: logits [32*64*64] fp32, xsum [32*512] fp32, then pre-split
  // weights: 4 x [64*512] ushort (qh, ql, kh, kl) — ~846 KB total
  float* logits = (float*)d_ws;
  float* xsum   = logits + CB * CO * CO;
  unsigned short* wbuf = (unsigned short*)(xsum + CB * CC);

  init_kernel<<<(ZERO_N + 255) / 256, 256, 0, stream>>>(wq, wk, wbuf, logits);
  proj_kernel<<<CB * (NN / NT), 256, 0, stream>>>(x, wbuf, bq, bk, logits, xsum);
  finalize_kernel<<<CB, 256, 0, stream>>>(wv, bv, logits, xsum, out);
}

// Round 8
// 396.423 us; speedup vs baseline: 1.0140x; 1.0140x over previous
//
#include <hip/hip_runtime.h>

// ---------------------------------------------------------------------------
// AttentionPooling: out[b,o] = sum_p softmax_over_o(qk^T)[o,p] * vbar[b,p]
//   q = wq x + bq, k = wk x + bk  (1x1 conv == GEMM, M=64 K=512 N=4096/batch)
//   vbar[b,p] = wv . mean_n x[b,:,n] + bv   (v never materialized)
// Precision: fp32 emulated via bf16 hi/lo split, 3 MFMA passes (wh*xh + wl*xh
// + wh*xl) accumulating fp32 -> ~2^-16 relative.
//
// R8 = R6 (398.5us best) + ONE change: the staging->MFMA barrier (barrier 2)
// no longer drains vmcnt. __syncthreads() emits s_waitcnt vmcnt(0) which
// forced the just-issued next-chunk x prefetch (~800cy remaining) to complete
// before MFMA could start. Replaced with lgkmcnt(0)+s_barrier: LDS writes
// drained (correctness), register-destined prefetch stays in flight under
// the MFMA phase. Barrier 1 (pre-overwrite) keeps full __syncthreads -- its
// drain is free (loads are consumed right after it anyway).
// In-flight vmem at barrier 2: x prefetch (private regs), xsum atomics (no
// intra-kernel reader), weight loads (already use-site-waited). All safe.
// History: (256,3)/(256,4) spill (R4/R5); KC=64 null (R7); swizzle null-but-
// harmless, kept (R6); weight presplit + 1-deep prefetch proven (R1).
// ---------------------------------------------------------------------------

typedef __attribute__((ext_vector_type(8))) short short8;          // 8 bf16
typedef __attribute__((ext_vector_type(4))) float floatx4;
typedef __attribute__((ext_vector_type(4))) unsigned short ushort4v;
typedef __attribute__((ext_vector_type(8))) unsigned short ushort8v;

#define MFMA16(a, b, c) __builtin_amdgcn_mfma_f32_16x16x32_bf16((a), (b), (c), 0, 0, 0)

__device__ __forceinline__ unsigned short f2bf(float f) {
  unsigned int u = __float_as_uint(f);
  u = u + 0x7fffu + ((u >> 16) & 1u);   // RNE
  return (unsigned short)(u >> 16);
}
__device__ __forceinline__ float bf2f(unsigned short h) {
  return __uint_as_float(((unsigned int)h) << 16);
}

// Barrier that drains LDS ops but NOT vmem: register-destined global loads
// stay in flight across it (compiler still emits use-site vmcnt waits).
__device__ __forceinline__ void barrier_no_vmem_drain() {
  asm volatile("s_waitcnt lgkmcnt(0)" ::: "memory");
  __builtin_amdgcn_s_barrier();
}

constexpr int CB = 32;        // batch
constexpr int CC = 512;       // channels
constexpr int CO = 64;        // C/8
constexpr int NN = 4096;      // H*W
constexpr int NT = 128;       // n-tile per workgroup
constexpr int KC = 32;        // c-chunk staged per iteration
constexpr int NCH = CC / KC;  // 16 chunks

// LDS row strides (ushort units). 40 dw%32 patterns give <=2-way conflicts on
// reads; writes fixed to 2-way by the slot swizzle. Rows 16B-aligned (80B).
constexpr int XROW = 40;      // staged rows: KC(32) + 8 pad
constexpr int QROW = 72;      // q/k tile rows: 64 + 8 pad

// LDS offsets (ushort units), projection phase:
constexpr int WQH = 0;        // wq hi  [64][40]
constexpr int WQL = 2560;     // wq lo
constexpr int WKH = 5120;     // wk hi
constexpr int WKL = 7680;     // wk lo
constexpr int XHI = 10240;    // x^T hi [128][40]
constexpr int XLO = 15360;    // x^T lo
constexpr int SMEM_U = 20480; // 40 KiB total
// logits phase overlays the same LDS (projection staging is dead by then):
constexpr int QHI = 0, QLO = 4608, KHI = 9216, KLO = 13824;  // [64][72] each

constexpr int WB_ELEMS = CO * CC;  // 32768 ushorts per array (qh, ql, kh, kl)
constexpr int ZERO_N = CB * CO * CO + CB * CC;  // 147456 floats to zero

// ---- fused: zero logits/xsum + one-time weight split to bf16 hi/lo --------
__global__ __launch_bounds__(256) void init_kernel(
    const float* __restrict__ wq, const float* __restrict__ wk,
    unsigned short* __restrict__ wbuf, float* __restrict__ zp)
{
  const int i = blockIdx.x * 256 + threadIdx.x;
  if (i < ZERO_N) zp[i] = 0.0f;
  if (i < WB_ELEMS) {
    const float q = wq[i], k = wk[i];
    const unsigned short qh = f2bf(q), kh = f2bf(k);
    wbuf[i]                 = qh;
    wbuf[WB_ELEMS + i]      = f2bf(q - bf2f(qh));
    wbuf[2 * WB_ELEMS + i]  = kh;
    wbuf[3 * WB_ELEMS + i]  = f2bf(k - bf2f(kh));
  }
}

__global__ __launch_bounds__(256, 2) void proj_kernel(
    const float* __restrict__ x, const unsigned short* __restrict__ wbuf,
    const float* __restrict__ bq, const float* __restrict__ bk,
    float* __restrict__ logits, float* __restrict__ xsum)
{
  __shared__ __align__(16) unsigned short smem[SMEM_U];

  const int t    = threadIdx.x;
  const int lane = t & 63;
  const int wave = t >> 6;
  const int quad = lane >> 4;
  const int l15  = lane & 15;
  const int b    = blockIdx.x >> 5;   // /32 tiles
  const int tile = blockIdx.x & 31;
  const int n0   = tile * NT;
  const int nlow = t & 31;            // n sub-index for staging
  const int chi  = t >> 5;            // c group 0..7 for staging
  const int wrow = t >> 2;            // weight-copy row 0..63
  const int wcf  = (t & 3) * 8;       // weight-copy col (ushorts)

  // x-staging swizzle (lane-constant): write slot8 index chi ^ (2*((n>>3)&1));
  // since n = i*32 + nlow, (n>>3)&1 == (nlow>>3)&1 for all i.
  const int chi_s  = chi ^ ((((nlow >> 3) & 1)) << 1);
  // fragment read: quad' = quad ^ ((nr>>3)&1) == quad ^ ((l15>>3)&1).
  const int quad_s = quad ^ ((l15 >> 3) & 1);

  floatx4 accq[4][2], acck[4][2];     // q,k tiles: 4 m-frags x 2 n-frags/wave
#pragma unroll
  for (int mf = 0; mf < 4; ++mf)
#pragma unroll
    for (int nf = 0; nf < 2; ++nf) {
      accq[mf][nf] = (floatx4)0.0f;
      acck[mf][nf] = (floatx4)0.0f;
    }

  const float* xb = x + (size_t)b * CC * NN + n0;

  // ---- prefetch chunk 0 into registers ----
  float xr[16];
#pragma unroll
  for (int i = 0; i < 4; ++i)
#pragma unroll
    for (int cj = 0; cj < 4; ++cj)
      xr[i * 4 + cj] = xb[(size_t)(chi * 4 + cj) * NN + i * 32 + nlow];

  for (int ch = 0; ch < NCH; ++ch) {
    const int c0 = ch * KC;
    __syncthreads();  // previous chunk's LDS reads done before overwrite
                      // (full drain is free here: prefetch is consumed next)

    // ---- issue weight copies early (L2-resident after first WG) ----
    const unsigned short* wsrc = wbuf + (size_t)wrow * CC + c0 + wcf;
    const ushort8v a0 = *reinterpret_cast<const ushort8v*>(wsrc);
    const ushort8v a1 = *reinterpret_cast<const ushort8v*>(wsrc + WB_ELEMS);
    const ushort8v a2 = *reinterpret_cast<const ushort8v*>(wsrc + 2 * WB_ELEMS);
    const ushort8v a3 = *reinterpret_cast<const ushort8v*>(wsrc + 3 * WB_ELEMS);

    // ---- convert prefetched x chunk -> LDS transposed [n][c] hi/lo ----
    // data for c-group chi lands in slot chi_s (involution; reader undoes it)
    float xs_part[4] = {0.f, 0.f, 0.f, 0.f};
#pragma unroll
    for (int i = 0; i < 4; ++i) {
      const int n = i * 32 + nlow;
      const float v0 = xr[i * 4 + 0], v1 = xr[i * 4 + 1];
      const float v2 = xr[i * 4 + 2], v3 = xr[i * 4 + 3];
      xs_part[0] += v0; xs_part[1] += v1; xs_part[2] += v2; xs_part[3] += v3;
      ushort4v h, l;
      h[0] = f2bf(v0); l[0] = f2bf(v0 - bf2f(h[0]));
      h[1] = f2bf(v1); l[1] = f2bf(v1 - bf2f(h[1]));
      h[2] = f2bf(v2); l[2] = f2bf(v2 - bf2f(h[2]));
      h[3] = f2bf(v3); l[3] = f2bf(v3 - bf2f(h[3]));
      *reinterpret_cast<ushort4v*>(&smem[XHI + n * XROW + chi_s * 4]) = h;
      *reinterpret_cast<ushort4v*>(&smem[XLO + n * XROW + chi_s * 4]) = l;
    }
#pragma unroll
    for (int j = 0; j < 4; ++j) {   // reduce 32 lanes (same c) -> 1 atomic
      float v = xs_part[j];
      v += __shfl_xor(v, 16); v += __shfl_xor(v, 8);
      v += __shfl_xor(v, 4);  v += __shfl_xor(v, 2); v += __shfl_xor(v, 1);
      if ((lane & 31) == 0) atomicAdd(&xsum[b * CC + c0 + chi * 4 + j], v);
    }

    // ---- weight copies into padded LDS rows (16B, 2-way max) ----
    *reinterpret_cast<ushort8v*>(&smem[WQH + wrow * XROW + wcf]) = a0;
    *reinterpret_cast<ushort8v*>(&smem[WQL + wrow * XROW + wcf]) = a1;
    *reinterpret_cast<ushort8v*>(&smem[WKH + wrow * XROW + wcf]) = a2;
    *reinterpret_cast<ushort8v*>(&smem[WKL + wrow * XROW + wcf]) = a3;

    // ---- prefetch next x chunk; stays in flight across barrier 2 ----
    if (ch + 1 < NCH) {
      const int c0n = c0 + KC;
#pragma unroll
      for (int i = 0; i < 4; ++i)
#pragma unroll
        for (int cj = 0; cj < 4; ++cj)
          xr[i * 4 + cj] = xb[(size_t)(c0n + chi * 4 + cj) * NN + i * 32 + nlow];
    }
    barrier_no_vmem_drain();  // LDS staged; do NOT drain the prefetch

    // ---- MFMA: wave w covers n-local [w*32, w*32+32) ----
    short8 xh[2], xl[2];
#pragma unroll
    for (int nf = 0; nf < 2; ++nf) {
      const int nr = wave * 32 + nf * 16 + l15;
      xh[nf] = *reinterpret_cast<const short8*>(&smem[XHI + nr * XROW + quad_s * 8]);
      xl[nf] = *reinterpret_cast<const short8*>(&smem[XLO + nr * XROW + quad_s * 8]);
    }
#pragma unroll
    for (int mf = 0; mf < 4; ++mf) {
      const int orow = mf * 16 + l15;
      const short8 aqh = *reinterpret_cast<const short8*>(&smem[WQH + orow * XROW + quad * 8]);
      const short8 aql = *reinterpret_cast<const short8*>(&smem[WQL + orow * XROW + quad * 8]);
      const short8 akh = *reinterpret_cast<const short8*>(&smem[WKH + orow * XROW + quad * 8]);
      const short8 akl = *reinterpret_cast<const short8*>(&smem[WKL + orow * XROW + quad * 8]);
#pragma unroll
      for (int nf = 0; nf < 2; ++nf) {
        accq[mf][nf] = MFMA16(aqh, xh[nf], accq[mf][nf]);
        accq[mf][nf] = MFMA16(aql, xh[nf], accq[mf][nf]);
        accq[mf][nf] = MFMA16(aqh, xl[nf], accq[mf][nf]);
        acck[mf][nf] = MFMA16(akh, xh[nf], acck[mf][nf]);
        acck[mf][nf] = MFMA16(akl, xh[nf], acck[mf][nf]);
        acck[mf][nf] = MFMA16(akh, xl[nf], acck[mf][nf]);
      }
    }
  }

  // ---- add biases (C/D layout: row o = mf*16 + quad*4 + reg, col = n) ----
#pragma unroll
  for (int mf = 0; mf < 4; ++mf)
#pragma unroll
    for (int r = 0; r < 4; ++r) {
      const int o = mf * 16 + quad * 4 + r;
      const float bqv = bq[o], bkv = bk[o];
#pragma unroll
      for (int nf = 0; nf < 2; ++nf) {
        accq[mf][nf][r] += bqv;
        acck[mf][nf][r] += bkv;
      }
    }

  // ---- logits partial: S = q k^T over this n-tile, K split in two halves ----
  floatx4 accS[4];
#pragma unroll
  for (int mf = 0; mf < 4; ++mf) accS[mf] = (floatx4)0.0f;

  for (int hh = 0; hh < 2; ++hh) {
    __syncthreads();
    if ((wave >> 1) == hh) {   // waves owning n-local [hh*64, hh*64+64) write
      const int nbase = (wave & 1) * 32;
#pragma unroll
      for (int mf = 0; mf < 4; ++mf)
#pragma unroll
        for (int nf = 0; nf < 2; ++nf)
#pragma unroll
          for (int r = 0; r < 4; ++r) {
            const int o  = mf * 16 + quad * 4 + r;
            const int nc = nbase + nf * 16 + l15;
            const float qv = accq[mf][nf][r];
            const float kv = acck[mf][nf][r];
            const unsigned short qh = f2bf(qv);
            const unsigned short kh = f2bf(kv);
            smem[QHI + o * QROW + nc] = qh;
            smem[QLO + o * QROW + nc] = f2bf(qv - bf2f(qh));
            smem[KHI + o * QROW + nc] = kh;
            smem[KLO + o * QROW + nc] = f2bf(kv - bf2f(kh));
          }
    }
    __syncthreads();
#pragma unroll
    for (int ks = 0; ks < 2; ++ks) {
      const short8 bh = *reinterpret_cast<const short8*>(
          &smem[KHI + (wave * 16 + l15) * QROW + ks * 32 + quad * 8]);
      const short8 bl = *reinterpret_cast<const short8*>(
          &smem[KLO + (wave * 16 + l15) * QROW + ks * 32 + quad * 8]);
#pragma unroll
      for (int mf = 0; mf < 4; ++mf) {
        const short8 ah = *reinterpret_cast<const short8*>(
            &smem[QHI + (mf * 16 + l15) * QROW + ks * 32 + quad * 8]);
        const short8 al = *reinterpret_cast<const short8*>(
            &smem[QLO + (mf * 16 + l15) * QROW + ks * 32 + quad * 8]);
        accS[mf] = MFMA16(ah, bh, accS[mf]);
        accS[mf] = MFMA16(al, bh, accS[mf]);
        accS[mf] = MFMA16(ah, bl, accS[mf]);
      }
    }
  }

  // accumulate into global logits[b][o][p]
#pragma unroll
  for (int mf = 0; mf < 4; ++mf)
#pragma unroll
    for (int r = 0; r < 4; ++r) {
      const int o = mf * 16 + quad * 4 + r;
      const int p = wave * 16 + l15;
      atomicAdd(&logits[((size_t)b * CO + o) * CO + p], accS[mf][r]);
    }
}

__global__ __launch_bounds__(256) void finalize_kernel(
    const float* __restrict__ wv, const float* __restrict__ bv,
    const float* __restrict__ logits, const float* __restrict__ xsum,
    float* __restrict__ out)
{
  __shared__ float ls[CO * 65];
  __shared__ float xs_s[CC];
  __shared__ float vbar_s[CO], w2_s[CO], cmax_s[CO];
  const int t = threadIdx.x;
  const int b = blockIdx.x;

  for (int i = t; i < CC; i += 256) xs_s[i] = xsum[b * CC + i];
#pragma unroll
  for (int i = 0; i < 16; ++i) {
    const int idx = t + i * 256;          // 0..4095
    ls[(idx >> 6) * 65 + (idx & 63)] = logits[(size_t)b * CO * CO + idx];
  }
  __syncthreads();

  // vbar[p] = (wv[p,:] . xsum[b,:]) / N + bv[p]; 4 threads per p
  {
    const int p = t >> 2, part = t & 3;
    float s = 0.f;
    const float* wr = wv + (size_t)p * CC + part * 128;
    const float* xr = xs_s + part * 128;
#pragma unroll 4
    for (int c = 0; c < 128; ++c) s += wr[c] * xr[c];
    s += __shfl_xor(s, 1); s += __shfl_xor(s, 2);
    if (part == 0) vbar_s[p] = s * (1.0f / 4096.0f) + bv[p];
  }
  __syncthreads();

  if (t < CO) {  // column stats: softmax over rows o for column p=t
    float m = -1e30f;
    for (int o = 0; o < CO; ++o) m = fmaxf(m, ls[o * 65 + t]);
    float sum = 0.f;
    for (int o = 0; o < CO; ++o) sum += __expf(ls[o * 65 + t] - m);
    cmax_s[t] = m;
    w2_s[t]   = vbar_s[t] / sum;
  }
  __syncthreads();

  if (t < CO) {  // out[b,o] = sum_p exp(l[o,p]-cmax[p]) * vbar[p]/colsum[p]
    float acc = 0.f;
    for (int p = 0; p < CO; ++p)
      acc += __expf(ls[t * 65 + p] - cmax_s[p]) * w2_s[p];
    out[b * CO + t] = acc;
  }
}

extern "C" void kernel_launch(void* const* d_in, const int* in_sizes, int n_in,
                              void* d_out, int out_size, void* d_ws, size_t ws_size,
                              hipStream_t stream) {
  const float* x  = (const float*)d_in[0];
  const float* wq = (const float*)d_in[1];
  const float* bq = (const float*)d_in[2];
  const float* wk = (const float*)d_in[3];
  const float* bk = (const float*)d_in[4];
  const float* wv = (const float*)d_in[5];
  const float* bv = (const float*)d_in[6];
  float* out = (float*)d_out;

  // workspace: logits [32*64*64] fp32, xsum [32*512] fp32, then pre-split
  // weights: 4 x [64*512] ushort (qh, ql, kh, kl) — ~846 KB total
  float* logits = (float*)d_ws;
  float* xsum   = logits + CB * CO * CO;
  unsigned short* wbuf = (unsigned short*)(xsum + CB * CC);

  init_kernel<<<(ZERO_N + 255) / 256, 256, 0, stream>>>(wq, wk, wbuf, logits);
  proj_kernel<<<CB * (NN / NT), 256, 0, stream>>>(x, wbuf, bq, bk, logits, xsum);
  finalize_kernel<<<CB, 256, 0, stream>>>(wv, bv, logits, xsum, out);
}